// Round 1
// baseline (779.469 us; speedup 1.0000x reference)
//
#include <hip/hip_runtime.h>
#include <math.h>

// Problem constants
#define B_   8
#define Q_   300
#define C_   256
#define NH_  8
#define NL_  4
#define NP_  4
#define DFF_ 1024
#define DH_  32
#define LEN_ 13294
#define MQ_  (B_*Q_)    // 2400
#define MV_  (B_*LEN_)  // 106352

// ---------------- elementwise add ----------------
__global__ __launch_bounds__(256) void k_add(const float* __restrict__ a,
                                             const float* __restrict__ b,
                                             float* __restrict__ o, int n) {
    int i = blockIdx.x * 256 + threadIdx.x;
    if (i < n) o[i] = a[i] + b[i];
}

// ---------------- generic fp32 GEMM: out[M,N] = A[M,K] @ W[K,N] + bias, opt ReLU ----------------
// block 16x16 threads, 64x64 tile, K-chunk 32, 4x4 micro-tile per thread
template<int RELU>
__global__ __launch_bounds__(256) void k_gemm(const float* __restrict__ A,
                                              const float* __restrict__ W,
                                              const float* __restrict__ bias,
                                              float* __restrict__ out,
                                              int M, int N, int K) {
    __shared__ float As[64][33];   // +1 pad: kills 16-way bank conflict on As[row][kk]
    __shared__ float Bs[32][64];   // 2-way on reads = free
    const int tid   = threadIdx.y * 16 + threadIdx.x;
    const int tileM = blockIdx.y * 64, tileN = blockIdx.x * 64;
    float acc[4][4] = {};
    const int ar = tid >> 5, ac = tid & 31;   // A-load: 8 rows apart
    const int br = tid >> 6, bc = tid & 63;   // B-load: 4 rows apart
    for (int k0 = 0; k0 < K; k0 += 32) {
#pragma unroll
        for (int i = 0; i < 8; ++i) {
            int r = tileM + ar + i * 8;
            As[ar + i * 8][ac] = (r < M) ? A[r * K + k0 + ac] : 0.f;
        }
#pragma unroll
        for (int i = 0; i < 8; ++i)
            Bs[br + i * 4][bc] = W[(k0 + br + i * 4) * N + tileN + bc];
        __syncthreads();
#pragma unroll
        for (int kk = 0; kk < 32; ++kk) {
            float a4[4], b4[4];
#pragma unroll
            for (int i = 0; i < 4; ++i) a4[i] = As[threadIdx.y * 4 + i][kk];
#pragma unroll
            for (int j = 0; j < 4; ++j) b4[j] = Bs[kk][threadIdx.x * 4 + j];
#pragma unroll
            for (int i = 0; i < 4; ++i)
#pragma unroll
                for (int j = 0; j < 4; ++j) acc[i][j] += a4[i] * b4[j];
        }
        __syncthreads();
    }
#pragma unroll
    for (int i = 0; i < 4; ++i) {
        int r = tileM + threadIdx.y * 4 + i;
        if (r < M) {
#pragma unroll
            for (int j = 0; j < 4; ++j) {
                int cc = tileN + threadIdx.x * 4 + j;
                float v = acc[i][j] + bias[cc];
                if (RELU) v = fmaxf(v, 0.f);
                out[r * N + cc] = v;
            }
        }
    }
}

// ---------------- attention scores: attn[b,h,i,j] = scale * q[b,i,h,:]·k[b,j,h,:] ----------------
__global__ __launch_bounds__(256) void k_scores(const float* __restrict__ q,
                                                const float* __restrict__ k,
                                                float* __restrict__ attn) {
    const int bh = blockIdx.x;            // 0..63
    const int b = bh >> 3, h = bh & 7;
    const int i0 = blockIdx.y * 75;       // 4 chunks of 75 rows
    __shared__ float kb[Q_][DH_ + 1];     // +1 pad: avoid same-bank column reads
    __shared__ float qb[DH_];
    const int tid = threadIdx.x;
    for (int idx = tid; idx < Q_ * DH_; idx += 256) {
        int r = idx >> 5, d = idx & 31;
        kb[r][d] = k[(b * Q_ + r) * C_ + h * DH_ + d];
    }
    __syncthreads();
    const float scale = 0.17677669529663687f;  // 1/sqrt(32)
    for (int i = i0; i < i0 + 75; ++i) {
        if (tid < DH_) qb[tid] = q[(b * Q_ + i) * C_ + h * DH_ + tid];
        __syncthreads();
        for (int j = tid; j < Q_; j += 256) {
            float s = 0.f;
#pragma unroll 8
            for (int d = 0; d < DH_; ++d) s += qb[d] * kb[j][d];
            attn[(bh * Q_ + i) * Q_ + j] = s * scale;
        }
        __syncthreads();
    }
}

// ---------------- row softmax over n elements (wave per row) ----------------
__global__ __launch_bounds__(256) void k_softmax_rows(float* __restrict__ attn, int rows, int n) {
    const int wid  = threadIdx.x >> 6;
    const int lane = threadIdx.x & 63;
    const int row  = blockIdx.x * 4 + wid;
    if (row >= rows) return;
    float* p = attn + (long)row * n;
    float vals[8];
    float mx = -1e30f;
    int cnt = 0;
    for (int j = lane; j < n; j += 64) { vals[cnt] = p[j]; mx = fmaxf(mx, vals[cnt]); ++cnt; }
#pragma unroll
    for (int off = 32; off; off >>= 1) mx = fmaxf(mx, __shfl_xor(mx, off));
    float sum = 0.f;
    for (int c = 0; c < cnt; ++c) { vals[c] = expf(vals[c] - mx); sum += vals[c]; }
#pragma unroll
    for (int off = 32; off; off >>= 1) sum += __shfl_xor(sum, off);
    float inv = 1.f / sum;
    cnt = 0;
    for (int j = lane; j < n; j += 64) { p[j] = vals[cnt] * inv; ++cnt; }
}

// ---------------- sa[b,i,h,d] = sum_j attn[b,h,i,j] * v[b,j,h,d] ----------------
__global__ __launch_bounds__(256) void k_av(const float* __restrict__ attn,
                                            const float* __restrict__ v,
                                            float* __restrict__ sa) {
    const int bh = blockIdx.x;
    const int b = bh >> 3, h = bh & 7;
    const int ii = threadIdx.x >> 5;
    const int d  = threadIdx.x & 31;
    const int i  = blockIdx.y * 8 + ii;
    if (i >= Q_) return;
    const float* ar = attn + (bh * Q_ + i) * Q_;
    float acc = 0.f;
    for (int j = 0; j < Q_; ++j)
        acc += ar[j] * v[(b * Q_ + j) * C_ + h * DH_ + d];
    sa[(b * Q_ + i) * C_ + h * DH_ + d] = acc;
}

// ---------------- LayerNorm(x + res) over C=256, block per row ----------------
__global__ __launch_bounds__(256) void k_ln(const float* __restrict__ x,
                                            const float* __restrict__ res,
                                            const float* __restrict__ g,
                                            const float* __restrict__ be,
                                            float* __restrict__ out, int rows) {
    const int row = blockIdx.x;
    const int tid = threadIdx.x;
    float v = x[row * C_ + tid] + res[row * C_ + tid];
    __shared__ float red[4];
    float s = v;
#pragma unroll
    for (int off = 32; off; off >>= 1) s += __shfl_xor(s, off);
    if ((tid & 63) == 0) red[tid >> 6] = s;
    __syncthreads();
    float mean = (red[0] + red[1] + red[2] + red[3]) * (1.f / C_);
    float dv = v - mean;
    float s2 = dv * dv;
    __syncthreads();
#pragma unroll
    for (int off = 32; off; off >>= 1) s2 += __shfl_xor(s2, off);
    if ((tid & 63) == 0) red[tid >> 6] = s2;
    __syncthreads();
    float var = (red[0] + red[1] + red[2] + red[3]) * (1.f / C_);
    float rstd = 1.f / sqrtf(var + 1e-5f);
    out[row * C_ + tid] = dv * rstd * g[tid] + be[tid];
}

// ---------------- softmax over 16 (NL*NP) per (b,q,h), in place ----------------
__global__ __launch_bounds__(256) void k_softmax16(float* __restrict__ aw) {
    const int t = blockIdx.x * 256 + threadIdx.x;   // (b*Q+q)*NH + h
    if (t >= MQ_ * NH_) return;
    float* p = aw + t * 16;   // (bq)*128 + h*16 == ((bq)*8+h)*16
    float v[16], mx = -1e30f;
#pragma unroll
    for (int j = 0; j < 16; ++j) { v[j] = p[j]; mx = fmaxf(mx, v[j]); }
    float s = 0.f;
#pragma unroll
    for (int j = 0; j < 16; ++j) { v[j] = expf(v[j] - mx); s += v[j]; }
    float inv = 1.f / s;
#pragma unroll
    for (int j = 0; j < 16; ++j) p[j] = v[j] * inv;
}

// ---------------- deformable bilinear sampling ----------------
// thread per (b,q,h,d); lanes d=0..31 coalesce on each gathered 128B row slice
__global__ __launch_bounds__(256) void k_sample(const float* __restrict__ value,
                                                const float* __restrict__ refp,
                                                const float* __restrict__ off,
                                                const float* __restrict__ aw,
                                                float* __restrict__ out) {
    const int t = blockIdx.x * 256 + threadIdx.x;
    const int d  = t & 31;
    const int g  = t >> 5;         // (b*Q+q)*NH + h
    const int h  = g & 7;
    const int bq = g >> 3;
    const int b  = bq / Q_;
    const int starts[4] = {0, 10000, 12500, 13125};
    const int HW[4]     = {100, 50, 25, 13};
    const float* offp = off + bq * 256 + h * 32;
    const float* awp  = aw + bq * 128 + h * 16;
    float acc = 0.f;
#pragma unroll
    for (int l = 0; l < NL_; ++l) {
        const int Hl = HW[l], Wl = HW[l], st = starts[l];
        const float rx = refp[(bq * NL_ + l) * 2 + 0];
        const float ry = refp[(bq * NL_ + l) * 2 + 1];
        const float* vbase = value + (b * LEN_ + st) * C_ + h * DH_ + d;
#pragma unroll
        for (int p = 0; p < NP_; ++p) {
            const float ox = offp[l * 8 + p * 2 + 0];
            const float oy = offp[l * 8 + p * 2 + 1];
            const float lx = rx + ox / (float)Wl;
            const float ly = ry + oy / (float)Hl;
            const float x = lx * (float)Wl - 0.5f;
            const float y = ly * (float)Hl - 0.5f;
            const float x0 = floorf(x), y0 = floorf(y);
            const float dx = x - x0, dy = y - y0;
            const int ix0 = (int)x0, iy0 = (int)y0;
            float sample = 0.f;
            // 4 corners
            {
                int xi = ix0, yi = iy0;
                if (xi >= 0 && xi < Wl && yi >= 0 && yi < Hl)
                    sample += (1.f - dx) * (1.f - dy) * vbase[(yi * Wl + xi) * C_];
            }
            {
                int xi = ix0 + 1, yi = iy0;
                if (xi >= 0 && xi < Wl && yi >= 0 && yi < Hl)
                    sample += dx * (1.f - dy) * vbase[(yi * Wl + xi) * C_];
            }
            {
                int xi = ix0, yi = iy0 + 1;
                if (xi >= 0 && xi < Wl && yi >= 0 && yi < Hl)
                    sample += (1.f - dx) * dy * vbase[(yi * Wl + xi) * C_];
            }
            {
                int xi = ix0 + 1, yi = iy0 + 1;
                if (xi >= 0 && xi < Wl && yi >= 0 && yi < Hl)
                    sample += dx * dy * vbase[(yi * Wl + xi) * C_];
            }
            acc += awp[l * 4 + p] * sample;
        }
    }
    out[bq * C_ + h * DH_ + d] = acc;
}

// ---------------- launch ----------------
extern "C" void kernel_launch(void* const* d_in, const int* in_sizes, int n_in,
                              void* d_out, int out_size, void* d_ws, size_t ws_size,
                              hipStream_t stream) {
    const float* tgt    = (const float*)d_in[0];
    const float* refp   = (const float*)d_in[1];
    const float* memory = (const float*)d_in[2];
    const float* qpe    = (const float*)d_in[3];
    const float* Wq     = (const float*)d_in[4];  const float* bq_  = (const float*)d_in[5];
    const float* Wk     = (const float*)d_in[6];  const float* bk_  = (const float*)d_in[7];
    const float* Wv     = (const float*)d_in[8];  const float* bv_  = (const float*)d_in[9];
    const float* Wo     = (const float*)d_in[10]; const float* bo_  = (const float*)d_in[11];
    const float* g1     = (const float*)d_in[12]; const float* be1  = (const float*)d_in[13];
    const float* W_off  = (const float*)d_in[14]; const float* b_off  = (const float*)d_in[15];
    const float* W_attn = (const float*)d_in[16]; const float* b_attn = (const float*)d_in[17];
    const float* W_val  = (const float*)d_in[18]; const float* b_val  = (const float*)d_in[19];
    const float* W_out  = (const float*)d_in[20]; const float* b_out  = (const float*)d_in[21];
    const float* g2     = (const float*)d_in[22]; const float* be2  = (const float*)d_in[23];
    const float* W1     = (const float*)d_in[24]; const float* b1   = (const float*)d_in[25];
    const float* W2     = (const float*)d_in[26]; const float* b2   = (const float*)d_in[27];
    const float* g3     = (const float*)d_in[28]; const float* be3  = (const float*)d_in[29];
    float* out = (float*)d_out;
    float* ws  = (float*)d_ws;

    // workspace layout (floats); peak = 33,062,912 floats = 132.3 MB
    float* t1    = ws;                 // 614400
    float* t2    = ws + 614400;        // 614400
    float* query = ws + 1228800;       // 614400
    float* offb  = ws + 1843200;       // 614400
    float* awb   = ws + 2457600;       // 307200
    float* dsout = ws + 2764800;       // 614400
    float* ff1   = ws + 3379200;       // 2457600
    float* U     = ws + 5836800;       // union region: 27,226,112 floats
    float* qk    = U;                  // phase 1
    float* qb    = U + 614400;
    float* kb    = U + 1228800;
    float* vb    = U + 1843200;
    float* attn  = U + 2457600;        // 5,760,000
    float* sa    = U + 8217600;        // 614400
    float* saO   = U;                  // reuse qk (free after q,k GEMMs)
    float* value = U;                  // phase 2 (overlays all of phase 1)
    float* ca    = U;                  // after sampling, value is dead
    float* ff2   = U + 614400;

    const dim3 gblk(16, 16);

    // ---- self-attention ----
    k_add<<<2400, 256, 0, stream>>>(tgt, qpe, qk, MQ_ * C_);
    k_gemm<0><<<dim3(4, 38), gblk, 0, stream>>>(qk, Wq, bq_, qb, MQ_, C_, C_);
    k_gemm<0><<<dim3(4, 38), gblk, 0, stream>>>(qk, Wk, bk_, kb, MQ_, C_, C_);
    k_gemm<0><<<dim3(4, 38), gblk, 0, stream>>>(tgt, Wv, bv_, vb, MQ_, C_, C_);
    k_scores<<<dim3(64, 4), 256, 0, stream>>>(qb, kb, attn);
    k_softmax_rows<<<4800, 256, 0, stream>>>(attn, B_ * NH_ * Q_, Q_);
    k_av<<<dim3(64, 38), 256, 0, stream>>>(attn, vb, sa);
    k_gemm<0><<<dim3(4, 38), gblk, 0, stream>>>(sa, Wo, bo_, saO, MQ_, C_, C_);
    k_ln<<<2400, 256, 0, stream>>>(tgt, saO, g1, be1, t1, MQ_);

    // ---- deformable cross-attention ----
    k_add<<<2400, 256, 0, stream>>>(t1, qpe, query, MQ_ * C_);
    k_gemm<0><<<dim3(4, 38), gblk, 0, stream>>>(query, W_off, b_off, offb, MQ_, 256, C_);
    k_gemm<0><<<dim3(2, 38), gblk, 0, stream>>>(query, W_attn, b_attn, awb, MQ_, 128, C_);
    k_softmax16<<<75, 256, 0, stream>>>(awb);
    k_gemm<0><<<dim3(4, 1662), gblk, 0, stream>>>(memory, W_val, b_val, value, MV_, C_, C_);
    k_sample<<<2400, 256, 0, stream>>>(value, refp, offb, awb, dsout);
    k_gemm<0><<<dim3(4, 38), gblk, 0, stream>>>(dsout, W_out, b_out, ca, MQ_, C_, C_);
    k_ln<<<2400, 256, 0, stream>>>(t1, ca, g2, be2, t2, MQ_);

    // ---- FFN ----
    k_gemm<1><<<dim3(16, 38), gblk, 0, stream>>>(t2, W1, b1, ff1, MQ_, DFF_, C_);
    k_gemm<0><<<dim3(4, 38), gblk, 0, stream>>>(ff1, W2, b2, ff2, MQ_, C_, DFF_);
    k_ln<<<2400, 256, 0, stream>>>(t2, ff2, g3, be3, out, MQ_);
}

// Round 2
// 459.648 us; speedup vs baseline: 1.6958x; 1.6958x over previous
//
#include <hip/hip_runtime.h>
#include <hip/hip_bf16.h>
#include <math.h>

// Problem constants
#define B_   8
#define Q_   300
#define C_   256
#define NH_  8
#define NL_  4
#define NP_  4
#define DFF_ 1024
#define DH_  32
#define LEN_ 13294
#define MQ_  (B_*Q_)    // 2400
#define MV_  (B_*LEN_)  // 106352

typedef __attribute__((ext_vector_type(4))) float f32x4;
typedef __attribute__((ext_vector_type(8))) short bf16x8;
typedef __hip_bfloat16 bf16;

#define GLOAD16(gp, lp) __builtin_amdgcn_global_load_lds( \
    (const __attribute__((address_space(1))) unsigned int*)(gp), \
    (__attribute__((address_space(3))) unsigned int*)(lp), 16, 0, 0)

// ---------------- fp32 -> bf16 convert (vectorized x8) ----------------
__global__ __launch_bounds__(256) void k_cvt(const float* __restrict__ in,
                                             bf16* __restrict__ o, int n8) {
    int i = blockIdx.x * 256 + threadIdx.x;
    const int stride = gridDim.x * 256;
    for (; i < n8; i += stride) {
        const float4* p = (const float4*)(in + (size_t)i * 8);
        float4 a = p[0], b = p[1];
        union { bf16 h[8]; uint4 u; } v;
        v.h[0] = __float2bfloat16(a.x); v.h[1] = __float2bfloat16(a.y);
        v.h[2] = __float2bfloat16(a.z); v.h[3] = __float2bfloat16(a.w);
        v.h[4] = __float2bfloat16(b.x); v.h[5] = __float2bfloat16(b.y);
        v.h[6] = __float2bfloat16(b.z); v.h[7] = __float2bfloat16(b.w);
        *(uint4*)(o + (size_t)i * 8) = v.u;
    }
}

// ---------------- out_bf16 = a + b ----------------
__global__ __launch_bounds__(256) void k_addcvt(const float* __restrict__ a,
                                                const float* __restrict__ b,
                                                bf16* __restrict__ o, int n8) {
    int i = blockIdx.x * 256 + threadIdx.x;
    const int stride = gridDim.x * 256;
    for (; i < n8; i += stride) {
        const float4* pa = (const float4*)(a + (size_t)i * 8);
        const float4* pb = (const float4*)(b + (size_t)i * 8);
        float4 x = pa[0], y = pa[1], u = pb[0], w = pb[1];
        union { bf16 h[8]; uint4 v; } v;
        v.h[0] = __float2bfloat16(x.x + u.x); v.h[1] = __float2bfloat16(x.y + u.y);
        v.h[2] = __float2bfloat16(x.z + u.z); v.h[3] = __float2bfloat16(x.w + u.w);
        v.h[4] = __float2bfloat16(y.x + w.x); v.h[5] = __float2bfloat16(y.y + w.y);
        v.h[6] = __float2bfloat16(y.z + w.z); v.h[7] = __float2bfloat16(y.w + w.w);
        *(uint4*)(o + (size_t)i * 8) = v.v;
    }
}

// ---------------- weight transpose+convert: W[K][N] -> Wt[N][K] bf16 ----------------
__global__ __launch_bounds__(256) void k_wt(const float* __restrict__ W,
                                            bf16* __restrict__ Wt, int K, int N) {
    __shared__ float t[32][33];
    const int n0 = blockIdx.x * 32, k0 = blockIdx.y * 32;
    const int c = threadIdx.x & 31, r = threadIdx.x >> 5;  // 8 rows/pass
#pragma unroll
    for (int i = 0; i < 4; ++i) {
        int k = k0 + r + i * 8, n = n0 + c;
        t[r + i * 8][c] = (k < K && n < N) ? W[(size_t)k * N + n] : 0.f;
    }
    __syncthreads();
#pragma unroll
    for (int i = 0; i < 4; ++i) {
        int n = n0 + r + i * 8, k = k0 + c;
        if (n < N && k < K) Wt[(size_t)n * K + k] = __float2bfloat16(t[c][r + i * 8]);
    }
}

// ---------------- bf16 MFMA GEMM: out[M,N] = A[M,K] @ Bt[N,K]^T + bias ----------------
// 128x128 tile, BK=32, 4 waves (2x2), each wave 64x64 = 4x4 frags of 16x16x32.
// OUT_MODE: 0 = fp32, 1 = bf16
template<int RELU, int OUT_MODE>
__global__ __launch_bounds__(256) void k_gmm(const bf16* __restrict__ A,
                                             const bf16* __restrict__ Bt,
                                             const float* __restrict__ bias,
                                             float* __restrict__ outf,
                                             bf16* __restrict__ outh,
                                             int M, int N, int K) {
    __shared__ bf16 As[128 * 32];
    __shared__ bf16 Bs[128 * 32];
    const int tid  = threadIdx.x;
    const int wid  = tid >> 6, lane = tid & 63;
    const int m0 = blockIdx.y * 128, n0 = blockIdx.x * 128;
    const int wr = wid >> 1, wc = wid & 1;       // wave 2x2
    const int fr = lane & 15, fq = lane >> 4;    // frag row/col, k-group
    const int rseg = lane >> 2;                  // staging: row in 16-row segment
    const int kof  = (lane & 3) * 8;             // staging: bf16 offset (16B chunks)
    f32x4 acc[4][4] = {};
    for (int k0 = 0; k0 < K; k0 += 32) {
        if (k0) __syncthreads();
#pragma unroll
        for (int s = 0; s < 2; ++s) {
            const int rloc = wid * 32 + s * 16;
            int gr = m0 + rloc + rseg; if (gr > M - 1) gr = M - 1;
            GLOAD16(A + (size_t)gr * K + k0 + kof, As + rloc * 32);
            int gc = n0 + rloc + rseg; if (gc > N - 1) gc = N - 1;
            GLOAD16(Bt + (size_t)gc * K + k0 + kof, Bs + rloc * 32);
        }
        __syncthreads();
        bf16x8 af[4], bfr[4];
#pragma unroll
        for (int m = 0; m < 4; ++m)
            af[m] = *(const bf16x8*)(As + (wr * 64 + m * 16 + fr) * 32 + fq * 8);
#pragma unroll
        for (int n = 0; n < 4; ++n)
            bfr[n] = *(const bf16x8*)(Bs + (wc * 64 + n * 16 + fr) * 32 + fq * 8);
#pragma unroll
        for (int m = 0; m < 4; ++m)
#pragma unroll
            for (int n = 0; n < 4; ++n)
                acc[m][n] = __builtin_amdgcn_mfma_f32_16x16x32_bf16(af[m], bfr[n], acc[m][n], 0, 0, 0);
    }
    // epilogue: C/D layout col=lane&15, row=(lane>>4)*4+reg
#pragma unroll
    for (int m = 0; m < 4; ++m) {
#pragma unroll
        for (int n = 0; n < 4; ++n) {
            const int c = n0 + wc * 64 + n * 16 + fr;
            if (c >= N) continue;
            const float bs = bias[c];
#pragma unroll
            for (int j = 0; j < 4; ++j) {
                const int r = m0 + wr * 64 + m * 16 + fq * 4 + j;
                if (r >= M) continue;
                float v = acc[m][n][j] + bs;
                if (RELU) v = fmaxf(v, 0.f);
                if (OUT_MODE == 0) outf[(size_t)r * N + c] = v;
                else               outh[(size_t)r * N + c] = __float2bfloat16(v);
            }
        }
    }
}

// ---------------- attention scores: attn[b,h,i,j] = scale * q.k ----------------
__global__ __launch_bounds__(256) void k_scores(const float* __restrict__ q,
                                                const float* __restrict__ k,
                                                float* __restrict__ attn) {
    const int bh = blockIdx.x;
    const int b = bh >> 3, h = bh & 7;
    const int i0 = blockIdx.y * 75;
    __shared__ float kb[Q_][DH_ + 1];
    __shared__ float qb[DH_];
    const int tid = threadIdx.x;
    for (int idx = tid; idx < Q_ * DH_; idx += 256) {
        int r = idx >> 5, d = idx & 31;
        kb[r][d] = k[(b * Q_ + r) * C_ + h * DH_ + d];
    }
    __syncthreads();
    const float scale = 0.17677669529663687f;
    for (int i = i0; i < i0 + 75; ++i) {
        if (tid < DH_) qb[tid] = q[(b * Q_ + i) * C_ + h * DH_ + tid];
        __syncthreads();
        for (int j = tid; j < Q_; j += 256) {
            float s = 0.f;
#pragma unroll 8
            for (int d = 0; d < DH_; ++d) s += qb[d] * kb[j][d];
            attn[((size_t)bh * Q_ + i) * Q_ + j] = s * scale;
        }
        __syncthreads();
    }
}

// ---------------- row softmax (wave per row) ----------------
__global__ __launch_bounds__(256) void k_softmax_rows(float* __restrict__ attn, int rows, int n) {
    const int wid = threadIdx.x >> 6, lane = threadIdx.x & 63;
    const int row = blockIdx.x * 4 + wid;
    if (row >= rows) return;
    float* p = attn + (size_t)row * n;
    float vals[8];
    float mx = -1e30f;
    int cnt = 0;
    for (int j = lane; j < n; j += 64) { vals[cnt] = p[j]; mx = fmaxf(mx, vals[cnt]); ++cnt; }
#pragma unroll
    for (int off = 32; off; off >>= 1) mx = fmaxf(mx, __shfl_xor(mx, off));
    float sum = 0.f;
    for (int c = 0; c < cnt; ++c) { vals[c] = expf(vals[c] - mx); sum += vals[c]; }
#pragma unroll
    for (int off = 32; off; off >>= 1) sum += __shfl_xor(sum, off);
    float inv = 1.f / sum;
    cnt = 0;
    for (int j = lane; j < n; j += 64) { p[j] = vals[cnt] * inv; ++cnt; }
}

// ---------------- sa_bf16[b,i,h,d] = sum_j attn[b,h,i,j] * v[b,j,h,d] ----------------
__global__ __launch_bounds__(256) void k_av(const float* __restrict__ attn,
                                            const float* __restrict__ v,
                                            bf16* __restrict__ sa) {
    const int bh = blockIdx.x;
    const int b = bh >> 3, h = bh & 7;
    const int ii = threadIdx.x >> 5;
    const int d  = threadIdx.x & 31;
    const int i  = blockIdx.y * 8 + ii;
    if (i >= Q_) return;
    const float* ar = attn + ((size_t)bh * Q_ + i) * Q_;
    float acc = 0.f;
    for (int j = 0; j < Q_; ++j)
        acc += ar[j] * v[(b * Q_ + j) * C_ + h * DH_ + d];
    sa[(b * Q_ + i) * C_ + h * DH_ + d] = __float2bfloat16(acc);
}

// ---------------- LayerNorm(x + res), optional bf16 copy ----------------
template<int WB>
__global__ __launch_bounds__(256) void k_ln(const float* __restrict__ x,
                                            const float* __restrict__ res,
                                            const float* __restrict__ g,
                                            const float* __restrict__ be,
                                            float* __restrict__ out,
                                            bf16* __restrict__ outh, int rows) {
    const int row = blockIdx.x;
    const int tid = threadIdx.x;
    float v = x[row * C_ + tid] + res[row * C_ + tid];
    __shared__ float red[4];
    float s = v;
#pragma unroll
    for (int off = 32; off; off >>= 1) s += __shfl_xor(s, off);
    if ((tid & 63) == 0) red[tid >> 6] = s;
    __syncthreads();
    float mean = (red[0] + red[1] + red[2] + red[3]) * (1.f / C_);
    float dv = v - mean;
    float s2 = dv * dv;
    __syncthreads();
#pragma unroll
    for (int off = 32; off; off >>= 1) s2 += __shfl_xor(s2, off);
    if ((tid & 63) == 0) red[tid >> 6] = s2;
    __syncthreads();
    float var = (red[0] + red[1] + red[2] + red[3]) * (1.f / C_);
    float rstd = 1.f / sqrtf(var + 1e-5f);
    float y = dv * rstd * g[tid] + be[tid];
    out[row * C_ + tid] = y;
    if (WB) outh[row * C_ + tid] = __float2bfloat16(y);
}

// ---------------- softmax over 16 per (b,q,h), in place ----------------
__global__ __launch_bounds__(256) void k_softmax16(float* __restrict__ aw) {
    const int t = blockIdx.x * 256 + threadIdx.x;
    if (t >= MQ_ * NH_) return;
    float* p = aw + t * 16;
    float v[16], mx = -1e30f;
#pragma unroll
    for (int j = 0; j < 16; ++j) { v[j] = p[j]; mx = fmaxf(mx, v[j]); }
    float s = 0.f;
#pragma unroll
    for (int j = 0; j < 16; ++j) { v[j] = expf(v[j] - mx); s += v[j]; }
    float inv = 1.f / s;
#pragma unroll
    for (int j = 0; j < 16; ++j) p[j] = v[j] * inv;
}

// ---------------- deformable bilinear sampling (value in bf16, out bf16) ----------------
__global__ __launch_bounds__(256) void k_sample(const bf16* __restrict__ value,
                                                const float* __restrict__ refp,
                                                const float* __restrict__ off,
                                                const float* __restrict__ aw,
                                                bf16* __restrict__ out) {
    const int t = blockIdx.x * 256 + threadIdx.x;
    const int d  = t & 31;
    const int g  = t >> 5;
    const int h  = g & 7;
    const int bq = g >> 3;
    const int b  = bq / Q_;
    const int starts[4] = {0, 10000, 12500, 13125};
    const int HW[4]     = {100, 50, 25, 13};
    const float* offp = off + bq * 256 + h * 32;
    const float* awp  = aw + bq * 128 + h * 16;
    float acc = 0.f;
#pragma unroll
    for (int l = 0; l < NL_; ++l) {
        const int Hl = HW[l], Wl = HW[l], st = starts[l];
        const float rx = refp[(bq * NL_ + l) * 2 + 0];
        const float ry = refp[(bq * NL_ + l) * 2 + 1];
        const bf16* vbase = value + ((size_t)b * LEN_ + st) * C_ + h * DH_ + d;
#pragma unroll
        for (int p = 0; p < NP_; ++p) {
            const float ox = offp[l * 8 + p * 2 + 0];
            const float oy = offp[l * 8 + p * 2 + 1];
            const float x = (rx + ox / (float)Wl) * (float)Wl - 0.5f;
            const float y = (ry + oy / (float)Hl) * (float)Hl - 0.5f;
            const float x0 = floorf(x), y0 = floorf(y);
            const float dx = x - x0, dy = y - y0;
            const int ix0 = (int)x0, iy0 = (int)y0;
            float sample = 0.f;
            { int xi = ix0,     yi = iy0;
              if (xi >= 0 && xi < Wl && yi >= 0 && yi < Hl)
                  sample += (1.f - dx) * (1.f - dy) * __bfloat162float(vbase[(yi * Wl + xi) * C_]); }
            { int xi = ix0 + 1, yi = iy0;
              if (xi >= 0 && xi < Wl && yi >= 0 && yi < Hl)
                  sample += dx * (1.f - dy) * __bfloat162float(vbase[(yi * Wl + xi) * C_]); }
            { int xi = ix0,     yi = iy0 + 1;
              if (xi >= 0 && xi < Wl && yi >= 0 && yi < Hl)
                  sample += (1.f - dx) * dy * __bfloat162float(vbase[(yi * Wl + xi) * C_]); }
            { int xi = ix0 + 1, yi = iy0 + 1;
              if (xi >= 0 && xi < Wl && yi >= 0 && yi < Hl)
                  sample += dx * dy * __bfloat162float(vbase[(yi * Wl + xi) * C_]); }
            acc += awp[l * 4 + p] * sample;
        }
    }
    out[bq * C_ + h * DH_ + d] = __float2bfloat16(acc);
}

// ---------------- launch ----------------
extern "C" void kernel_launch(void* const* d_in, const int* in_sizes, int n_in,
                              void* d_out, int out_size, void* d_ws, size_t ws_size,
                              hipStream_t stream) {
    const float* tgt    = (const float*)d_in[0];
    const float* refp   = (const float*)d_in[1];
    const float* memory = (const float*)d_in[2];
    const float* qpe    = (const float*)d_in[3];
    const float* Wq     = (const float*)d_in[4];  const float* bq_  = (const float*)d_in[5];
    const float* Wk     = (const float*)d_in[6];  const float* bk_  = (const float*)d_in[7];
    const float* Wv     = (const float*)d_in[8];  const float* bv_  = (const float*)d_in[9];
    const float* Wo     = (const float*)d_in[10]; const float* bo_  = (const float*)d_in[11];
    const float* g1     = (const float*)d_in[12]; const float* be1  = (const float*)d_in[13];
    const float* W_off  = (const float*)d_in[14]; const float* b_off  = (const float*)d_in[15];
    const float* W_attn = (const float*)d_in[16]; const float* b_attn = (const float*)d_in[17];
    const float* W_val  = (const float*)d_in[18]; const float* b_val  = (const float*)d_in[19];
    const float* W_out  = (const float*)d_in[20]; const float* b_out  = (const float*)d_in[21];
    const float* g2     = (const float*)d_in[22]; const float* be2  = (const float*)d_in[23];
    const float* W1     = (const float*)d_in[24]; const float* b1   = (const float*)d_in[25];
    const float* W2     = (const float*)d_in[26]; const float* b2   = (const float*)d_in[27];
    const float* g3     = (const float*)d_in[28]; const float* be3  = (const float*)d_in[29];
    float* out = (float*)d_out;

    // ---- workspace layout (bytes, 256-aligned) ----
    char* base = (char*)d_ws;
    size_t off = 0;
    auto alloc = [&](size_t bytes) -> char* {
        char* p = base + off; off = (off + bytes + 255) & ~(size_t)255; return p;
    };
    float* t1        = (float*)alloc(MQ_ * C_ * 4);
    float* offb      = (float*)alloc(MQ_ * 256 * 4);
    float* awb       = (float*)alloc(MQ_ * 128 * 4);
    bf16*  query_bf  = (bf16*) alloc(MQ_ * C_ * 2);
    bf16*  dsout_bf  = (bf16*) alloc(MQ_ * C_ * 2);
    bf16*  Wq_t   = (bf16*)alloc(C_ * C_ * 2);
    bf16*  Wk_t   = (bf16*)alloc(C_ * C_ * 2);
    bf16*  Wv_t   = (bf16*)alloc(C_ * C_ * 2);
    bf16*  Wo_t   = (bf16*)alloc(C_ * C_ * 2);
    bf16*  Wval_t = (bf16*)alloc(C_ * C_ * 2);
    bf16*  Woff_t = (bf16*)alloc(C_ * 256 * 2);
    bf16*  Wout_t = (bf16*)alloc(C_ * C_ * 2);
    bf16*  Wattn_t= (bf16*)alloc(C_ * 128 * 2);
    bf16*  W1_t   = (bf16*)alloc(C_ * DFF_ * 2);
    bf16*  W2_t   = (bf16*)alloc(C_ * DFF_ * 2);
    bf16*  mem_bf = (bf16*)alloc((size_t)MV_ * C_ * 2);
    char*  U      = alloc((size_t)MV_ * C_ * 2);   // union region, 54.45 MB
    // phase-1 (self-attention) overlay in U
    bf16*  qk_bf  = (bf16*)(U);
    bf16*  tgt_bf = (bf16*)(U + 1228800);
    float* qb     = (float*)(U + 2457600);
    float* kb     = (float*)(U + 4915200 + 2457600 - 2457600);     // U+4915200
    float* vb     = (float*)(U + 7372800);
    float* attn   = (float*)(U + 9830400);
    bf16*  sa_bf  = (bf16*) (U + 9830400 + 23040000);
    float* saO    = (float*)(U + 9830400 + 23040000 + 1228800);
    // phase-2 overlay
    bf16*  value_bf = (bf16*)(U);
    // phase-3 overlay
    float* ca     = (float*)(U);
    float* t2     = (float*)(U + 2457600);
    bf16*  t2_bf  = (bf16*) (U + 4915200);
    bf16*  ff1_bf = (bf16*) (U + 6144000);
    float* ff2    = (float*)(U + 11059200);

    const int gx256 = 2, gx128 = 1, gy2400 = (MQ_ + 127) / 128;   // 19
    const int gyV = (MV_ + 127) / 128;                            // 831

    // ---- conversions / weight prep ----
    k_cvt<<<2048, 256, 0, stream>>>(memory, mem_bf, MV_ * C_ / 8);
    k_wt<<<dim3(8, 8),  256, 0, stream>>>(Wq,     Wq_t,   C_, C_);
    k_wt<<<dim3(8, 8),  256, 0, stream>>>(Wk,     Wk_t,   C_, C_);
    k_wt<<<dim3(8, 8),  256, 0, stream>>>(Wv,     Wv_t,   C_, C_);
    k_wt<<<dim3(8, 8),  256, 0, stream>>>(Wo,     Wo_t,   C_, C_);
    k_wt<<<dim3(8, 8),  256, 0, stream>>>(W_val,  Wval_t, C_, C_);
    k_wt<<<dim3(8, 8),  256, 0, stream>>>(W_off,  Woff_t, C_, 256);
    k_wt<<<dim3(8, 8),  256, 0, stream>>>(W_out,  Wout_t, C_, C_);
    k_wt<<<dim3(4, 8),  256, 0, stream>>>(W_attn, Wattn_t,C_, 128);
    k_wt<<<dim3(32, 8), 256, 0, stream>>>(W1,     W1_t,   C_, DFF_);
    k_wt<<<dim3(8, 32), 256, 0, stream>>>(W2,     W2_t,   DFF_, C_);
    k_addcvt<<<300, 256, 0, stream>>>(tgt, qpe, qk_bf, MQ_ * C_ / 8);
    k_cvt<<<300, 256, 0, stream>>>(tgt, tgt_bf, MQ_ * C_ / 8);

    // ---- self-attention ----
    k_gmm<0,0><<<dim3(gx256, gy2400), 256, 0, stream>>>(qk_bf,  Wq_t, bq_, qb, nullptr, MQ_, C_, C_);
    k_gmm<0,0><<<dim3(gx256, gy2400), 256, 0, stream>>>(qk_bf,  Wk_t, bk_, kb, nullptr, MQ_, C_, C_);
    k_gmm<0,0><<<dim3(gx256, gy2400), 256, 0, stream>>>(tgt_bf, Wv_t, bv_, vb, nullptr, MQ_, C_, C_);
    k_scores<<<dim3(64, 4), 256, 0, stream>>>(qb, kb, attn);
    k_softmax_rows<<<4800, 256, 0, stream>>>(attn, B_ * NH_ * Q_, Q_);
    k_av<<<dim3(64, 38), 256, 0, stream>>>(attn, vb, sa_bf);
    k_gmm<0,0><<<dim3(gx256, gy2400), 256, 0, stream>>>(sa_bf, Wo_t, bo_, saO, nullptr, MQ_, C_, C_);
    k_ln<0><<<2400, 256, 0, stream>>>(tgt, saO, g1, be1, t1, nullptr, MQ_);

    // ---- deformable cross-attention ----
    k_addcvt<<<300, 256, 0, stream>>>(t1, qpe, query_bf, MQ_ * C_ / 8);
    k_gmm<0,0><<<dim3(gx256, gy2400), 256, 0, stream>>>(query_bf, Woff_t,  b_off,  offb, nullptr, MQ_, 256, C_);
    k_gmm<0,0><<<dim3(gx128, gy2400), 256, 0, stream>>>(query_bf, Wattn_t, b_attn, awb,  nullptr, MQ_, 128, C_);
    k_softmax16<<<75, 256, 0, stream>>>(awb);
    k_gmm<0,1><<<dim3(gx256, gyV), 256, 0, stream>>>(mem_bf, Wval_t, b_val, nullptr, value_bf, MV_, C_, C_);
    k_sample<<<2400, 256, 0, stream>>>(value_bf, refp, offb, awb, dsout_bf);
    k_gmm<0,0><<<dim3(gx256, gy2400), 256, 0, stream>>>(dsout_bf, Wout_t, b_out, ca, nullptr, MQ_, C_, C_);
    k_ln<1><<<2400, 256, 0, stream>>>(t1, ca, g2, be2, t2, t2_bf, MQ_);

    // ---- FFN ----
    k_gmm<1,1><<<dim3(8, gy2400), 256, 0, stream>>>(t2_bf, W1_t, b1, nullptr, ff1_bf, MQ_, DFF_, C_);
    k_gmm<0,0><<<dim3(gx256, gy2400), 256, 0, stream>>>(ff1_bf, W2_t, b2, ff2, nullptr, MQ_, C_, DFF_);
    k_ln<0><<<2400, 256, 0, stream>>>(t2, ff2, g3, be3, out, nullptr, MQ_);
}

// Round 4
// 244.882 us; speedup vs baseline: 3.1830x; 1.8770x over previous
//
#include <hip/hip_runtime.h>
#include <hip/hip_bf16.h>
#include <math.h>

// Problem constants
#define B_   8
#define Q_   300
#define C_   256
#define NH_  8
#define NL_  4
#define NP_  4
#define DFF_ 1024
#define DH_  32
#define LEN_ 13294
#define MQ_  (B_*Q_)    // 2400
#define MV_  (B_*LEN_)  // 106352

typedef __attribute__((ext_vector_type(4))) float f32x4;
typedef __attribute__((ext_vector_type(8))) short bf16x8;
typedef __hip_bfloat16 bf16;

#define GLOAD16(gp, lp) __builtin_amdgcn_global_load_lds( \
    (const __attribute__((address_space(1))) unsigned int*)(gp), \
    (__attribute__((address_space(3))) unsigned int*)(lp), 16, 0, 0)

// bit-preserving float -> bf16 bits (avoid short->bf16 numeric-conversion trap)
__device__ __forceinline__ short f2bfbits(float x) {
    bf16 h = __float2bfloat16(x);
    return *reinterpret_cast<short*>(&h);
}

// ---------------- fp32 -> bf16 convert (vectorized x8) ----------------
__global__ __launch_bounds__(256) void k_cvt(const float* __restrict__ in,
                                             bf16* __restrict__ o, int n8) {
    int i = blockIdx.x * 256 + threadIdx.x;
    const int stride = gridDim.x * 256;
    for (; i < n8; i += stride) {
        const float4* p = (const float4*)(in + (size_t)i * 8);
        float4 a = p[0], b = p[1];
        union { bf16 h[8]; uint4 u; } v;
        v.h[0] = __float2bfloat16(a.x); v.h[1] = __float2bfloat16(a.y);
        v.h[2] = __float2bfloat16(a.z); v.h[3] = __float2bfloat16(a.w);
        v.h[4] = __float2bfloat16(b.x); v.h[5] = __float2bfloat16(b.y);
        v.h[6] = __float2bfloat16(b.z); v.h[7] = __float2bfloat16(b.w);
        *(uint4*)(o + (size_t)i * 8) = v.u;
    }
}

// ---------------- out_bf16 = a + b ----------------
__global__ __launch_bounds__(256) void k_addcvt(const float* __restrict__ a,
                                                const float* __restrict__ b,
                                                bf16* __restrict__ o, int n8) {
    int i = blockIdx.x * 256 + threadIdx.x;
    const int stride = gridDim.x * 256;
    for (; i < n8; i += stride) {
        const float4* pa = (const float4*)(a + (size_t)i * 8);
        const float4* pb = (const float4*)(b + (size_t)i * 8);
        float4 x = pa[0], y = pa[1], u = pb[0], w = pb[1];
        union { bf16 h[8]; uint4 v; } v;
        v.h[0] = __float2bfloat16(x.x + u.x); v.h[1] = __float2bfloat16(x.y + u.y);
        v.h[2] = __float2bfloat16(x.z + u.z); v.h[3] = __float2bfloat16(x.w + u.w);
        v.h[4] = __float2bfloat16(y.x + w.x); v.h[5] = __float2bfloat16(y.y + w.y);
        v.h[6] = __float2bfloat16(y.z + w.z); v.h[7] = __float2bfloat16(y.w + w.w);
        *(uint4*)(o + (size_t)i * 8) = v.v;
    }
}

// ---------------- weight transpose+convert: W[K][N] -> Wt[N][K] bf16 ----------------
__global__ __launch_bounds__(256) void k_wt(const float* __restrict__ W,
                                            bf16* __restrict__ Wt, int K, int N) {
    __shared__ float t[32][33];
    const int n0 = blockIdx.x * 32, k0 = blockIdx.y * 32;
    const int c = threadIdx.x & 31, r = threadIdx.x >> 5;
#pragma unroll
    for (int i = 0; i < 4; ++i) {
        int k = k0 + r + i * 8, n = n0 + c;
        t[r + i * 8][c] = (k < K && n < N) ? W[(size_t)k * N + n] : 0.f;
    }
    __syncthreads();
#pragma unroll
    for (int i = 0; i < 4; ++i) {
        int n = n0 + r + i * 8, k = k0 + c;
        if (n < N && k < K) Wt[(size_t)n * K + k] = __float2bfloat16(t[c][r + i * 8]);
    }
}

// ---------------- 128x128 MFMA GEMM (for the big value projection) ----------------
template<int RELU, int OUT_MODE>
__global__ __launch_bounds__(256) void k_gmm(const bf16* __restrict__ A,
                                             const bf16* __restrict__ Bt,
                                             const float* __restrict__ bias,
                                             float* __restrict__ outf,
                                             bf16* __restrict__ outh,
                                             int M, int N, int K) {
    __shared__ bf16 As[128 * 32];
    __shared__ bf16 Bs[128 * 32];
    const int tid  = threadIdx.x;
    const int wid  = tid >> 6, lane = tid & 63;
    const int m0 = blockIdx.y * 128, n0 = blockIdx.x * 128;
    const int wr = wid >> 1, wc = wid & 1;
    const int fr = lane & 15, fq = lane >> 4;
    const int rseg = lane >> 2;
    const int kof  = (lane & 3) * 8;
    f32x4 acc[4][4] = {};
    for (int k0 = 0; k0 < K; k0 += 32) {
        if (k0) __syncthreads();
#pragma unroll
        for (int s = 0; s < 2; ++s) {
            const int rloc = wid * 32 + s * 16;
            int gr = m0 + rloc + rseg; if (gr > M - 1) gr = M - 1;
            GLOAD16(A + (size_t)gr * K + k0 + kof, As + rloc * 32);
            int gc = n0 + rloc + rseg; if (gc > N - 1) gc = N - 1;
            GLOAD16(Bt + (size_t)gc * K + k0 + kof, Bs + rloc * 32);
        }
        __syncthreads();
        bf16x8 af[4], bfr[4];
#pragma unroll
        for (int m = 0; m < 4; ++m)
            af[m] = *(const bf16x8*)(As + (wr * 64 + m * 16 + fr) * 32 + fq * 8);
#pragma unroll
        for (int n = 0; n < 4; ++n)
            bfr[n] = *(const bf16x8*)(Bs + (wc * 64 + n * 16 + fr) * 32 + fq * 8);
#pragma unroll
        for (int m = 0; m < 4; ++m)
#pragma unroll
            for (int n = 0; n < 4; ++n)
                acc[m][n] = __builtin_amdgcn_mfma_f32_16x16x32_bf16(af[m], bfr[n], acc[m][n], 0, 0, 0);
    }
#pragma unroll
    for (int m = 0; m < 4; ++m) {
#pragma unroll
        for (int n = 0; n < 4; ++n) {
            const int c = n0 + wc * 64 + n * 16 + fr;
            if (c >= N) continue;
            const float bs = bias[c];
#pragma unroll
            for (int j = 0; j < 4; ++j) {
                const int r = m0 + wr * 64 + m * 16 + fq * 4 + j;
                if (r >= M) continue;
                float v = acc[m][n][j] + bs;
                if (RELU) v = fmaxf(v, 0.f);
                if (OUT_MODE == 0) outf[(size_t)r * N + c] = v;
                else               outh[(size_t)r * N + c] = __float2bfloat16(v);
            }
        }
    }
}

// ---------------- 64x64 MFMA GEMM (high occupancy, dual bias) ----------------
template<int RELU, int OUT_MODE>
__global__ __launch_bounds__(256) void k_gmm64(const bf16* __restrict__ A,
                                               const bf16* __restrict__ Bt,
                                               const float* __restrict__ bias0,
                                               const float* __restrict__ bias1,
                                               int nsplit,
                                               float* __restrict__ outf,
                                               bf16* __restrict__ outh,
                                               int M, int N, int K) {
    __shared__ bf16 As[64 * 32];
    __shared__ bf16 Bs[64 * 32];
    const int tid  = threadIdx.x;
    const int wid  = tid >> 6, lane = tid & 63;
    const int m0 = blockIdx.y * 64, n0 = blockIdx.x * 64;
    const int wr = wid >> 1, wc = wid & 1;       // 2x2 waves of 32x32
    const int fr = lane & 15, fq = lane >> 4;
    const int rloc = wid * 16 + (lane >> 2);
    const int kof  = (lane & 3) * 8;
    f32x4 acc[2][2] = {};
    for (int k0 = 0; k0 < K; k0 += 32) {
        if (k0) __syncthreads();
        int gr = m0 + rloc; if (gr > M - 1) gr = M - 1;
        GLOAD16(A + (size_t)gr * K + k0 + kof, As + rloc * 32);
        int gc = n0 + rloc; if (gc > N - 1) gc = N - 1;
        GLOAD16(Bt + (size_t)gc * K + k0 + kof, Bs + rloc * 32);
        __syncthreads();
        bf16x8 af[2], bfr[2];
#pragma unroll
        for (int m = 0; m < 2; ++m)
            af[m] = *(const bf16x8*)(As + (wr * 32 + m * 16 + fr) * 32 + fq * 8);
#pragma unroll
        for (int n = 0; n < 2; ++n)
            bfr[n] = *(const bf16x8*)(Bs + (wc * 32 + n * 16 + fr) * 32 + fq * 8);
#pragma unroll
        for (int m = 0; m < 2; ++m)
#pragma unroll
            for (int n = 0; n < 2; ++n)
                acc[m][n] = __builtin_amdgcn_mfma_f32_16x16x32_bf16(af[m], bfr[n], acc[m][n], 0, 0, 0);
    }
#pragma unroll
    for (int m = 0; m < 2; ++m) {
#pragma unroll
        for (int n = 0; n < 2; ++n) {
            const int c = n0 + wc * 32 + n * 16 + fr;
            const float bs = (c < nsplit) ? bias0[c] : bias1[c - nsplit];
#pragma unroll
            for (int j = 0; j < 4; ++j) {
                const int r = m0 + wr * 32 + m * 16 + fq * 4 + j;
                if (r >= M) continue;
                float v = acc[m][n][j] + bs;
                if (RELU) v = fmaxf(v, 0.f);
                if (OUT_MODE == 0) outf[(size_t)r * N + c] = v;
                else               outh[(size_t)r * N + c] = __float2bfloat16(v);
            }
        }
    }
}

// ---------------- fused self-attention: QK^T -> softmax -> PV ----------------
// grid (5 qchunks, 64 bh), 4 waves; q,k in qk2 [2400][512] bf16 (q|k), v in vb [2400][256]
// All LDS tiles are short-typed (raw bf16 bits) to avoid numeric-conversion traps.
__global__ __launch_bounds__(256) void k_attn(const bf16* __restrict__ qk2,
                                              const bf16* __restrict__ vb,
                                              bf16* __restrict__ sa) {
    __shared__ short Ks[304][40];       // [key][d], stride 40 => conflict-free frag reads
    __shared__ short Vt[32][328];       // [d][key] transposed
    __shared__ short Ps[4][16][168];    // per-wave P half-tile [qrow][key_local]
    const int tid = threadIdx.x, w = tid >> 6, lane = tid & 63;
    const int fr = lane & 15, fq = lane >> 4;
    const int bh = blockIdx.y, b = bh >> 3, h = bh & 7;
    const int qbase = blockIdx.x * 64;

    // stage K rows and transposed V
    for (int k0 = 0; k0 < 300; k0 += 64) {
        int key = k0 + (tid >> 2);
        int dc = (tid & 3) * 8;
        if (key < 300) {
            *(bf16x8*)&Ks[key][dc] =
                *(const bf16x8*)&qk2[((size_t)(b * 300 + key)) * 512 + 256 + h * 32 + dc];
            bf16x8 v8 = *(const bf16x8*)&vb[((size_t)(b * 300 + key)) * 256 + h * 32 + dc];
#pragma unroll
            for (int i = 0; i < 8; ++i) Vt[dc + i][key] = v8[i];   // short = short: bit copy
        }
    }
    for (int i = tid; i < 32 * 20; i += 256) Vt[i & 31][300 + (i >> 5)] = 0;

    // Q A-fragment straight from global
    int qrow = qbase + w * 16 + fr;
    int qr = qrow < 300 ? qrow : 299;
    bf16x8 qf = *(const bf16x8*)&qk2[((size_t)(b * 300 + qr)) * 512 + h * 32 + fq * 8];
    __syncthreads();

    // S = Q K^T (19 key tiles of 16)
    f32x4 s[19];
#pragma unroll
    for (int kf = 0; kf < 19; ++kf) {
        bf16x8 kfr = *(const bf16x8*)&Ks[kf * 16 + fr][fq * 8];
        f32x4 z = {};
        s[kf] = __builtin_amdgcn_mfma_f32_16x16x32_bf16(qf, kfr, z, 0, 0, 0);
    }
    const float scale = 0.17677669529663687f;
#pragma unroll
    for (int kf = 0; kf < 19; ++kf)
#pragma unroll
        for (int j = 0; j < 4; ++j) s[kf][j] *= scale;
    if (288 + fr >= 300) {
#pragma unroll
        for (int j = 0; j < 4; ++j) s[18][j] = -1e30f;
    }
    // softmax over rows (row j spread over the 16 lanes of this fq group)
    float mx[4], sm[4], inv[4];
#pragma unroll
    for (int j = 0; j < 4; ++j) {
        mx[j] = s[0][j];
#pragma unroll
        for (int kf = 1; kf < 19; ++kf) mx[j] = fmaxf(mx[j], s[kf][j]);
    }
#pragma unroll
    for (int off = 1; off < 16; off <<= 1)
#pragma unroll
        for (int j = 0; j < 4; ++j) mx[j] = fmaxf(mx[j], __shfl_xor(mx[j], off));
#pragma unroll
    for (int j = 0; j < 4; ++j) sm[j] = 0.f;
#pragma unroll
    for (int kf = 0; kf < 19; ++kf)
#pragma unroll
        for (int j = 0; j < 4; ++j) { s[kf][j] = expf(s[kf][j] - mx[j]); sm[j] += s[kf][j]; }
#pragma unroll
    for (int off = 1; off < 16; off <<= 1)
#pragma unroll
        for (int j = 0; j < 4; ++j) sm[j] += __shfl_xor(sm[j], off);
#pragma unroll
    for (int j = 0; j < 4; ++j) inv[j] = 1.f / sm[j];

    // PV in two key-halves (Ps per-wave private; wave-synchronous LDS, DS in-order per wave)
    f32x4 o[2] = {};
#pragma unroll
    for (int half = 0; half < 2; ++half) {
        const int kfbeg = half * 10, kfend = half ? 19 : 10;
#pragma unroll
        for (int kf = kfbeg; kf < kfend; ++kf) {
            int gcol = kf * 16 + fr, lcol = gcol - half * 160;
            bool valid = gcol < 300;
#pragma unroll
            for (int j = 0; j < 4; ++j)
                Ps[w][fq * 4 + j][lcol] = valid ? f2bfbits(s[kf][j] * inv[j]) : (short)0;
        }
        if (half) {  // zero local cols 144..159 (global 304..319)
            int r = lane >> 2, c0 = 144 + (lane & 3) * 4;
#pragma unroll
            for (int i = 0; i < 4; ++i) Ps[w][r][c0 + i] = 0;
        }
#pragma unroll
        for (int ks = 0; ks < 5; ++ks) {
            bf16x8 pa = *(const bf16x8*)&Ps[w][fr][ks * 32 + fq * 8];
#pragma unroll
            for (int n = 0; n < 2; ++n) {
                bf16x8 vf = *(const bf16x8*)&Vt[n * 16 + fr][half * 160 + ks * 32 + fq * 8];
                o[n] = __builtin_amdgcn_mfma_f32_16x16x32_bf16(pa, vf, o[n], 0, 0, 0);
            }
        }
    }
    // store: row = qbase + w*16 + fq*4 + j, col d = n*16 + fr
#pragma unroll
    for (int n = 0; n < 2; ++n)
#pragma unroll
        for (int j = 0; j < 4; ++j) {
            int row = qbase + w * 16 + fq * 4 + j;
            if (row < 300)
                sa[((size_t)(b * 300 + row)) * 256 + h * 32 + n * 16 + fr] = __float2bfloat16(o[n][j]);
        }
}

// ---------------- LayerNorm(x + res), optional bf16 copy ----------------
template<int WB>
__global__ __launch_bounds__(256) void k_ln(const float* __restrict__ x,
                                            const float* __restrict__ res,
                                            const float* __restrict__ g,
                                            const float* __restrict__ be,
                                            float* __restrict__ out,
                                            bf16* __restrict__ outh, int rows) {
    const int row = blockIdx.x;
    const int tid = threadIdx.x;
    float v = x[row * C_ + tid] + res[row * C_ + tid];
    __shared__ float red[4];
    float s = v;
#pragma unroll
    for (int off = 32; off; off >>= 1) s += __shfl_xor(s, off);
    if ((tid & 63) == 0) red[tid >> 6] = s;
    __syncthreads();
    float mean = (red[0] + red[1] + red[2] + red[3]) * (1.f / C_);
    float dv = v - mean;
    float s2 = dv * dv;
    __syncthreads();
#pragma unroll
    for (int off = 32; off; off >>= 1) s2 += __shfl_xor(s2, off);
    if ((tid & 63) == 0) red[tid >> 6] = s2;
    __syncthreads();
    float var = (red[0] + red[1] + red[2] + red[3]) * (1.f / C_);
    float rstd = 1.f / sqrtf(var + 1e-5f);
    float y = dv * rstd * g[tid] + be[tid];
    out[row * C_ + tid] = y;
    if (WB) outh[row * C_ + tid] = __float2bfloat16(y);
}

// ---------------- softmax over 16 per (b,q,h) inside fused offaw buffer ----------------
__global__ __launch_bounds__(256) void k_softmax16(float* __restrict__ offaw) {
    const int t = blockIdx.x * 256 + threadIdx.x;
    if (t >= MQ_ * NH_) return;
    const int bq = t >> 3, h = t & 7;
    float* p = offaw + (size_t)bq * 384 + 256 + h * 16;
    float v[16], mx = -1e30f;
#pragma unroll
    for (int j = 0; j < 16; ++j) { v[j] = p[j]; mx = fmaxf(mx, v[j]); }
    float s = 0.f;
#pragma unroll
    for (int j = 0; j < 16; ++j) { v[j] = expf(v[j] - mx); s += v[j]; }
    float inv = 1.f / s;
#pragma unroll
    for (int j = 0; j < 16; ++j) p[j] = v[j] * inv;
}

// ---------------- deformable bilinear sampling ----------------
__global__ __launch_bounds__(256) void k_sample(const bf16* __restrict__ value,
                                                const float* __restrict__ refp,
                                                const float* __restrict__ offaw,
                                                bf16* __restrict__ out) {
    const int t = blockIdx.x * 256 + threadIdx.x;
    const int d  = t & 31;
    const int g  = t >> 5;
    const int h  = g & 7;
    const int bq = g >> 3;
    const int b  = bq / Q_;
    const int starts[4] = {0, 10000, 12500, 13125};
    const int HW[4]     = {100, 50, 25, 13};
    const float* offp = offaw + (size_t)bq * 384 + h * 32;
    const float* awp  = offaw + (size_t)bq * 384 + 256 + h * 16;
    float acc = 0.f;
#pragma unroll
    for (int l = 0; l < NL_; ++l) {
        const int Hl = HW[l], Wl = HW[l], st = starts[l];
        const float rx = refp[(bq * NL_ + l) * 2 + 0];
        const float ry = refp[(bq * NL_ + l) * 2 + 1];
        const bf16* vbase = value + ((size_t)b * LEN_ + st) * C_ + h * DH_ + d;
#pragma unroll
        for (int p = 0; p < NP_; ++p) {
            const float ox = offp[l * 8 + p * 2 + 0];
            const float oy = offp[l * 8 + p * 2 + 1];
            const float x = (rx + ox / (float)Wl) * (float)Wl - 0.5f;
            const float y = (ry + oy / (float)Hl) * (float)Hl - 0.5f;
            const float x0 = floorf(x), y0 = floorf(y);
            const float dx = x - x0, dy = y - y0;
            const int ix0 = (int)x0, iy0 = (int)y0;
            float sample = 0.f;
            { int xi = ix0,     yi = iy0;
              if (xi >= 0 && xi < Wl && yi >= 0 && yi < Hl)
                  sample += (1.f - dx) * (1.f - dy) * __bfloat162float(vbase[(yi * Wl + xi) * C_]); }
            { int xi = ix0 + 1, yi = iy0;
              if (xi >= 0 && xi < Wl && yi >= 0 && yi < Hl)
                  sample += dx * (1.f - dy) * __bfloat162float(vbase[(yi * Wl + xi) * C_]); }
            { int xi = ix0,     yi = iy0 + 1;
              if (xi >= 0 && xi < Wl && yi >= 0 && yi < Hl)
                  sample += (1.f - dx) * dy * __bfloat162float(vbase[(yi * Wl + xi) * C_]); }
            { int xi = ix0 + 1, yi = iy0 + 1;
              if (xi >= 0 && xi < Wl && yi >= 0 && yi < Hl)
                  sample += dx * dy * __bfloat162float(vbase[(yi * Wl + xi) * C_]); }
            acc += awp[l * 4 + p] * sample;
        }
    }
    out[(size_t)bq * C_ + h * DH_ + d] = __float2bfloat16(acc);
}

// ---------------- launch ----------------
extern "C" void kernel_launch(void* const* d_in, const int* in_sizes, int n_in,
                              void* d_out, int out_size, void* d_ws, size_t ws_size,
                              hipStream_t stream) {
    const float* tgt    = (const float*)d_in[0];
    const float* refp   = (const float*)d_in[1];
    const float* memory = (const float*)d_in[2];
    const float* qpe    = (const float*)d_in[3];
    const float* Wq     = (const float*)d_in[4];  const float* bq_  = (const float*)d_in[5];
    const float* Wk     = (const float*)d_in[6];  const float* bk_  = (const float*)d_in[7];
    const float* Wv     = (const float*)d_in[8];  const float* bv_  = (const float*)d_in[9];
    const float* Wo     = (const float*)d_in[10]; const float* bo_  = (const float*)d_in[11];
    const float* g1     = (const float*)d_in[12]; const float* be1  = (const float*)d_in[13];
    const float* W_off  = (const float*)d_in[14]; const float* b_off  = (const float*)d_in[15];
    const float* W_attn = (const float*)d_in[16]; const float* b_attn = (const float*)d_in[17];
    const float* W_val  = (const float*)d_in[18]; const float* b_val  = (const float*)d_in[19];
    const float* W_out  = (const float*)d_in[20]; const float* b_out  = (const float*)d_in[21];
    const float* g2     = (const float*)d_in[22]; const float* be2  = (const float*)d_in[23];
    const float* W1     = (const float*)d_in[24]; const float* b1   = (const float*)d_in[25];
    const float* W2     = (const float*)d_in[26]; const float* b2   = (const float*)d_in[27];
    const float* g3     = (const float*)d_in[28]; const float* be3  = (const float*)d_in[29];
    float* out = (float*)d_out;

    // ---- workspace layout ----
    char* base = (char*)d_ws;
    size_t off = 0;
    auto alloc = [&](size_t bytes) -> char* {
        char* p = base + off; off = (off + bytes + 255) & ~(size_t)255; return p;
    };
    float* t1       = (float*)alloc(MQ_ * C_ * 4);
    float* offaw    = (float*)alloc((size_t)MQ_ * 384 * 4);
    bf16*  query_bf = (bf16*) alloc(MQ_ * C_ * 2);
    bf16*  dsout_bf = (bf16*) alloc(MQ_ * C_ * 2);
    bf16*  Wqk_t  = (bf16*)alloc(512 * C_ * 2);     // Wq | Wk transposed
    bf16*  Wv_t   = (bf16*)alloc(C_ * C_ * 2);
    bf16*  Wo_t   = (bf16*)alloc(C_ * C_ * 2);
    bf16*  Wval_t = (bf16*)alloc(C_ * C_ * 2);
    bf16*  Woa_t  = (bf16*)alloc(384 * C_ * 2);     // W_off | W_attn transposed
    bf16*  Wout_t = (bf16*)alloc(C_ * C_ * 2);
    bf16*  W1_t   = (bf16*)alloc(C_ * DFF_ * 2);
    bf16*  W2_t   = (bf16*)alloc(DFF_ * C_ * 2);
    bf16*  mem_bf = (bf16*)alloc((size_t)MV_ * C_ * 2);
    char*  U      = alloc((size_t)MV_ * C_ * 2);    // union region, 54.45 MB
    // phase-1 overlay
    bf16*  qk_bf  = (bf16*)(U);                     // tgt + qpe
    bf16*  tgt_bf = (bf16*)(U + 1228800);
    bf16*  qkbuf  = (bf16*)(U + 2457600);           // [2400][512] q|k
    bf16*  vb     = (bf16*)(U + 4915200);           // [2400][256]
    bf16*  sa_bf  = (bf16*)(U + 6144000);
    float* saO    = (float*)(U + 7372800);
    // phase-2 overlay
    bf16*  value_bf = (bf16*)(U);
    // phase-3 overlay
    float* ca     = (float*)(U);
    float* t2     = (float*)(U + 2457600);
    bf16*  t2_bf  = (bf16*) (U + 4915200);
    bf16*  ff1_bf = (bf16*) (U + 6144000);
    float* ff2    = (float*)(U + 11059200);

    // ---- conversions / weight prep ----
    k_cvt<<<2048, 256, 0, stream>>>(memory, mem_bf, MV_ * C_ / 8);
    k_wt<<<dim3(8, 8),  256, 0, stream>>>(Wq,     Wqk_t,          C_, C_);
    k_wt<<<dim3(8, 8),  256, 0, stream>>>(Wk,     Wqk_t + 65536,  C_, C_);
    k_wt<<<dim3(8, 8),  256, 0, stream>>>(Wv,     Wv_t,   C_, C_);
    k_wt<<<dim3(8, 8),  256, 0, stream>>>(Wo,     Wo_t,   C_, C_);
    k_wt<<<dim3(8, 8),  256, 0, stream>>>(W_val,  Wval_t, C_, C_);
    k_wt<<<dim3(8, 8),  256, 0, stream>>>(W_off,  Woa_t,          C_, 256);
    k_wt<<<dim3(4, 8),  256, 0, stream>>>(W_attn, Woa_t + 65536,  C_, 128);
    k_wt<<<dim3(8, 8),  256, 0, stream>>>(W_out,  Wout_t, C_, C_);
    k_wt<<<dim3(32, 8), 256, 0, stream>>>(W1,     W1_t,   C_, DFF_);
    k_wt<<<dim3(8, 32), 256, 0, stream>>>(W2,     W2_t,   DFF_, C_);
    k_addcvt<<<300, 256, 0, stream>>>(tgt, qpe, qk_bf, MQ_ * C_ / 8);
    k_cvt<<<300, 256, 0, stream>>>(tgt, tgt_bf, MQ_ * C_ / 8);

    // ---- self-attention ----
    k_gmm64<0,1><<<dim3(8, 38), 256, 0, stream>>>(qk_bf,  Wqk_t, bq_, bk_, 256, nullptr, qkbuf, MQ_, 512, C_);
    k_gmm64<0,1><<<dim3(4, 38), 256, 0, stream>>>(tgt_bf, Wv_t,  bv_, bv_, 256, nullptr, vb,    MQ_, 256, C_);
    k_attn<<<dim3(5, 64), 256, 0, stream>>>(qkbuf, vb, sa_bf);
    k_gmm64<0,0><<<dim3(4, 38), 256, 0, stream>>>(sa_bf, Wo_t, bo_, bo_, 256, saO, nullptr, MQ_, 256, C_);
    k_ln<0><<<2400, 256, 0, stream>>>(tgt, saO, g1, be1, t1, nullptr, MQ_);

    // ---- deformable cross-attention ----
    k_addcvt<<<300, 256, 0, stream>>>(t1, qpe, query_bf, MQ_ * C_ / 8);
    k_gmm64<0,0><<<dim3(6, 38), 256, 0, stream>>>(query_bf, Woa_t, b_off, b_attn, 256, offaw, nullptr, MQ_, 384, C_);
    k_softmax16<<<75, 256, 0, stream>>>(offaw);
    k_gmm<0,1><<<dim3(2, 831), 256, 0, stream>>>(mem_bf, Wval_t, b_val, nullptr, value_bf, MV_, C_, C_);
    k_sample<<<2400, 256, 0, stream>>>(value_bf, refp, offaw, dsout_bf);
    k_gmm64<0,0><<<dim3(4, 38), 256, 0, stream>>>(dsout_bf, Wout_t, b_out, b_out, 256, ca, nullptr, MQ_, 256, C_);
    k_ln<1><<<2400, 256, 0, stream>>>(t1, ca, g2, be2, t2, t2_bf, MQ_);

    // ---- FFN ----
    k_gmm64<1,1><<<dim3(16, 38), 256, 0, stream>>>(t2_bf, W1_t, b1, b1, DFF_, nullptr, ff1_bf, MQ_, DFF_, C_);
    k_gmm64<0,0><<<dim3(4, 38), 256, 0, stream>>>(ff1_bf, W2_t, b2, b2, 256, ff2, nullptr, MQ_, C_, DFF_);
    k_ln<0><<<2400, 256, 0, stream>>>(t2, ff2, g3, be3, out, nullptr, MQ_);
}

// Round 5
// 206.420 us; speedup vs baseline: 3.7761x; 1.1863x over previous
//
#include <hip/hip_runtime.h>
#include <hip/hip_bf16.h>
#include <math.h>

// Problem constants
#define B_   8
#define Q_   300
#define C_   256
#define NH_  8
#define NL_  4
#define NP_  4
#define DFF_ 1024
#define DH_  32
#define LEN_ 13294
#define MQ_  (B_*Q_)    // 2400
#define MV_  (B_*LEN_)  // 106352

typedef __attribute__((ext_vector_type(4))) float f32x4;
typedef __attribute__((ext_vector_type(8))) short bf16x8;
typedef __hip_bfloat16 bf16;

#define GLOAD16(gp, lp) __builtin_amdgcn_global_load_lds( \
    (const __attribute__((address_space(1))) unsigned int*)(gp), \
    (__attribute__((address_space(3))) unsigned int*)(lp), 16, 0, 0)

// bit-preserving float -> bf16 bits (avoid short->bf16 numeric-conversion trap)
__device__ __forceinline__ short f2bfbits(float x) {
    bf16 h = __float2bfloat16(x);
    return *reinterpret_cast<short*>(&h);
}

// ---------------- dual convert: qk_bf = bf16(tgt+qpe), tgt_bf = bf16(tgt) ----------------
__global__ __launch_bounds__(256) void k_dualcvt(const float* __restrict__ tgt,
                                                 const float* __restrict__ qpe,
                                                 bf16* __restrict__ qk_o,
                                                 bf16* __restrict__ tgt_o, int n8) {
    int i = blockIdx.x * 256 + threadIdx.x;
    if (i >= n8) return;
    const float4* pa = (const float4*)(tgt + (size_t)i * 8);
    const float4* pb = (const float4*)(qpe + (size_t)i * 8);
    float4 x = pa[0], y = pa[1], u = pb[0], w = pb[1];
    union { bf16 h[8]; uint4 v; } s, t;
    s.h[0] = __float2bfloat16(x.x + u.x); s.h[1] = __float2bfloat16(x.y + u.y);
    s.h[2] = __float2bfloat16(x.z + u.z); s.h[3] = __float2bfloat16(x.w + u.w);
    s.h[4] = __float2bfloat16(y.x + w.x); s.h[5] = __float2bfloat16(y.y + w.y);
    s.h[6] = __float2bfloat16(y.z + w.z); s.h[7] = __float2bfloat16(y.w + w.w);
    t.h[0] = __float2bfloat16(x.x); t.h[1] = __float2bfloat16(x.y);
    t.h[2] = __float2bfloat16(x.z); t.h[3] = __float2bfloat16(x.w);
    t.h[4] = __float2bfloat16(y.x); t.h[5] = __float2bfloat16(y.y);
    t.h[6] = __float2bfloat16(y.z); t.h[7] = __float2bfloat16(y.w);
    *(uint4*)(qk_o + (size_t)i * 8)  = s.v;
    *(uint4*)(tgt_o + (size_t)i * 8) = t.v;
}

// ---------------- all weight transposes in one launch ----------------
// 992 blocks; each transposes one 32x32 tile of some W[K][N] -> Wt[N][K] bf16
__global__ __launch_bounds__(256) void k_wtall(
        const float* __restrict__ Wq, const float* __restrict__ Wk,
        const float* __restrict__ Wv, const float* __restrict__ Wo,
        const float* __restrict__ Wval, const float* __restrict__ Woff,
        const float* __restrict__ Wattn, const float* __restrict__ Wout,
        const float* __restrict__ W1, const float* __restrict__ W2,
        bf16* __restrict__ Wqk_t, bf16* __restrict__ Wv_t, bf16* __restrict__ Wo_t,
        bf16* __restrict__ Wval_t, bf16* __restrict__ Woa_t, bf16* __restrict__ Wout_t,
        bf16* __restrict__ W1_t, bf16* __restrict__ W2_t) {
    __shared__ float t[32][33];
    const int id = blockIdx.x;
    const float* W; bf16* D; int K, N, r;
    if      (id < 64)  { W = Wq;    D = Wqk_t;          K = 256;  N = 256;  r = id; }
    else if (id < 128) { W = Wk;    D = Wqk_t + 65536;  K = 256;  N = 256;  r = id - 64; }
    else if (id < 192) { W = Wv;    D = Wv_t;           K = 256;  N = 256;  r = id - 128; }
    else if (id < 256) { W = Wo;    D = Wo_t;           K = 256;  N = 256;  r = id - 192; }
    else if (id < 320) { W = Wval;  D = Wval_t;         K = 256;  N = 256;  r = id - 256; }
    else if (id < 384) { W = Woff;  D = Woa_t;          K = 256;  N = 256;  r = id - 320; }
    else if (id < 416) { W = Wattn; D = Woa_t + 65536;  K = 256;  N = 128;  r = id - 384; }
    else if (id < 480) { W = Wout;  D = Wout_t;         K = 256;  N = 256;  r = id - 416; }
    else if (id < 736) { W = W1;    D = W1_t;           K = 256;  N = 1024; r = id - 480; }
    else               { W = W2;    D = W2_t;           K = 1024; N = 256;  r = id - 736; }
    const int nx = N >> 5;
    const int k0 = (r / nx) * 32, n0 = (r % nx) * 32;
    const int c = threadIdx.x & 31, rr = threadIdx.x >> 5;
#pragma unroll
    for (int i = 0; i < 4; ++i)
        t[rr + i * 8][c] = W[(size_t)(k0 + rr + i * 8) * N + n0 + c];
    __syncthreads();
#pragma unroll
    for (int i = 0; i < 4; ++i)
        D[(size_t)(n0 + rr + i * 8) * K + k0 + c] = __float2bfloat16(t[c][rr + i * 8]);
}

// ---------------- value GEMM with fused fp32->bf16 A conversion ----------------
// out_bf16[M,N] = bf16(fp32 A[M,K]) @ Bt[N,K]^T + bias ; 128x128 tile, BK=32
__global__ __launch_bounds__(256) void k_gmmV(const float* __restrict__ A,
                                              const bf16* __restrict__ Bt,
                                              const float* __restrict__ bias,
                                              bf16* __restrict__ outh,
                                              int M, int N, int K) {
    __shared__ bf16 As[128 * 32];
    __shared__ bf16 Bs[128 * 32];
    const int tid  = threadIdx.x;
    const int wid  = tid >> 6, lane = tid & 63;
    const int m0 = blockIdx.y * 128, n0 = blockIdx.x * 128;
    const int wr = wid >> 1, wc = wid & 1;
    const int fr = lane & 15, fq = lane >> 4;
    const int rseg = lane >> 2;
    const int kof  = (lane & 3) * 8;
    const int arow = tid >> 1, acol = (tid & 1) * 16;   // A staging: 16 fp32 per thread
    f32x4 acc[4][4] = {};
    for (int k0 = 0; k0 < K; k0 += 32) {
        if (k0) __syncthreads();
        // A: fp32 global -> regs -> bf16 -> LDS
        {
            int gr = m0 + arow; if (gr > M - 1) gr = M - 1;
            const float4* ap = (const float4*)(A + (size_t)gr * K + k0 + acol);
            float4 a0 = ap[0], a1 = ap[1], a2 = ap[2], a3 = ap[3];
            union { bf16 h[16]; uint4 u[2]; } cv;
            cv.h[0]  = __float2bfloat16(a0.x); cv.h[1]  = __float2bfloat16(a0.y);
            cv.h[2]  = __float2bfloat16(a0.z); cv.h[3]  = __float2bfloat16(a0.w);
            cv.h[4]  = __float2bfloat16(a1.x); cv.h[5]  = __float2bfloat16(a1.y);
            cv.h[6]  = __float2bfloat16(a1.z); cv.h[7]  = __float2bfloat16(a1.w);
            cv.h[8]  = __float2bfloat16(a2.x); cv.h[9]  = __float2bfloat16(a2.y);
            cv.h[10] = __float2bfloat16(a2.z); cv.h[11] = __float2bfloat16(a2.w);
            cv.h[12] = __float2bfloat16(a3.x); cv.h[13] = __float2bfloat16(a3.y);
            cv.h[14] = __float2bfloat16(a3.z); cv.h[15] = __float2bfloat16(a3.w);
            *(uint4*)(As + arow * 32 + acol)     = cv.u[0];
            *(uint4*)(As + arow * 32 + acol + 8) = cv.u[1];
        }
        // B: async global->LDS
#pragma unroll
        for (int s = 0; s < 2; ++s) {
            const int rloc = wid * 32 + s * 16;
            int gc = n0 + rloc + rseg; if (gc > N - 1) gc = N - 1;
            GLOAD16(Bt + (size_t)gc * K + k0 + kof, Bs + rloc * 32);
        }
        __syncthreads();
        bf16x8 af[4], bfr[4];
#pragma unroll
        for (int m = 0; m < 4; ++m)
            af[m] = *(const bf16x8*)(As + (wr * 64 + m * 16 + fr) * 32 + fq * 8);
#pragma unroll
        for (int n = 0; n < 4; ++n)
            bfr[n] = *(const bf16x8*)(Bs + (wc * 64 + n * 16 + fr) * 32 + fq * 8);
#pragma unroll
        for (int m = 0; m < 4; ++m)
#pragma unroll
            for (int n = 0; n < 4; ++n)
                acc[m][n] = __builtin_amdgcn_mfma_f32_16x16x32_bf16(af[m], bfr[n], acc[m][n], 0, 0, 0);
    }
#pragma unroll
    for (int m = 0; m < 4; ++m) {
#pragma unroll
        for (int n = 0; n < 4; ++n) {
            const int c = n0 + wc * 64 + n * 16 + fr;
            if (c >= N) continue;
            const float bs = bias[c];
#pragma unroll
            for (int j = 0; j < 4; ++j) {
                const int r = m0 + wr * 64 + m * 16 + fq * 4 + j;
                if (r >= M) continue;
                outh[(size_t)r * N + c] = __float2bfloat16(acc[m][n][j] + bs);
            }
        }
    }
}

// ---------------- 64x64 MFMA GEMM (high occupancy, dual bias) ----------------
template<int RELU, int OUT_MODE>
__global__ __launch_bounds__(256) void k_gmm64(const bf16* __restrict__ A,
                                               const bf16* __restrict__ Bt,
                                               const float* __restrict__ bias0,
                                               const float* __restrict__ bias1,
                                               int nsplit,
                                               float* __restrict__ outf,
                                               bf16* __restrict__ outh,
                                               int M, int N, int K) {
    __shared__ bf16 As[64 * 32];
    __shared__ bf16 Bs[64 * 32];
    const int tid  = threadIdx.x;
    const int wid  = tid >> 6, lane = tid & 63;
    const int m0 = blockIdx.y * 64, n0 = blockIdx.x * 64;
    const int wr = wid >> 1, wc = wid & 1;       // 2x2 waves of 32x32
    const int fr = lane & 15, fq = lane >> 4;
    const int rloc = wid * 16 + (lane >> 2);
    const int kof  = (lane & 3) * 8;
    f32x4 acc[2][2] = {};
    for (int k0 = 0; k0 < K; k0 += 32) {
        if (k0) __syncthreads();
        int gr = m0 + rloc; if (gr > M - 1) gr = M - 1;
        GLOAD16(A + (size_t)gr * K + k0 + kof, As + rloc * 32);
        int gc = n0 + rloc; if (gc > N - 1) gc = N - 1;
        GLOAD16(Bt + (size_t)gc * K + k0 + kof, Bs + rloc * 32);
        __syncthreads();
        bf16x8 af[2], bfr[2];
#pragma unroll
        for (int m = 0; m < 2; ++m)
            af[m] = *(const bf16x8*)(As + (wr * 32 + m * 16 + fr) * 32 + fq * 8);
#pragma unroll
        for (int n = 0; n < 2; ++n)
            bfr[n] = *(const bf16x8*)(Bs + (wc * 32 + n * 16 + fr) * 32 + fq * 8);
#pragma unroll
        for (int m = 0; m < 2; ++m)
#pragma unroll
            for (int n = 0; n < 2; ++n)
                acc[m][n] = __builtin_amdgcn_mfma_f32_16x16x32_bf16(af[m], bfr[n], acc[m][n], 0, 0, 0);
    }
#pragma unroll
    for (int m = 0; m < 2; ++m) {
#pragma unroll
        for (int n = 0; n < 2; ++n) {
            const int c = n0 + wc * 32 + n * 16 + fr;
            const float bs = (c < nsplit) ? bias0[c] : bias1[c - nsplit];
#pragma unroll
            for (int j = 0; j < 4; ++j) {
                const int r = m0 + wr * 32 + m * 16 + fq * 4 + j;
                if (r >= M) continue;
                float v = acc[m][n][j] + bs;
                if (RELU) v = fmaxf(v, 0.f);
                if (OUT_MODE == 0) outf[(size_t)r * N + c] = v;
                else               outh[(size_t)r * N + c] = __float2bfloat16(v);
            }
        }
    }
}

// ---------------- fused self-attention: QK^T -> softmax -> PV ----------------
// grid (5 qchunks, 64 bh), 4 waves; q,k in qk2 [2400][512] bf16 (q|k), v in vb [2400][256]
__global__ __launch_bounds__(256) void k_attn(const bf16* __restrict__ qk2,
                                              const bf16* __restrict__ vb,
                                              bf16* __restrict__ sa) {
    __shared__ short Ks[304][40];       // [key][d], stride 40 => conflict-free frag reads
    __shared__ short Vt[32][328];       // [d][key] transposed
    __shared__ short Ps[4][16][168];    // per-wave P half-tile [qrow][key_local]
    const int tid = threadIdx.x, w = tid >> 6, lane = tid & 63;
    const int fr = lane & 15, fq = lane >> 4;
    const int bh = blockIdx.y, b = bh >> 3, h = bh & 7;
    const int qbase = blockIdx.x * 64;

    // stage K rows and transposed V
    for (int k0 = 0; k0 < 300; k0 += 64) {
        int key = k0 + (tid >> 2);
        int dc = (tid & 3) * 8;
        if (key < 300) {
            *(bf16x8*)&Ks[key][dc] =
                *(const bf16x8*)&qk2[((size_t)(b * 300 + key)) * 512 + 256 + h * 32 + dc];
            bf16x8 v8 = *(const bf16x8*)&vb[((size_t)(b * 300 + key)) * 256 + h * 32 + dc];
#pragma unroll
            for (int i = 0; i < 8; ++i) Vt[dc + i][key] = v8[i];   // short = short: bit copy
        }
    }
    for (int i = tid; i < 32 * 20; i += 256) Vt[i & 31][300 + (i >> 5)] = 0;

    // Q A-fragment straight from global
    int qrow = qbase + w * 16 + fr;
    int qr = qrow < 300 ? qrow : 299;
    bf16x8 qf = *(const bf16x8*)&qk2[((size_t)(b * 300 + qr)) * 512 + h * 32 + fq * 8];
    __syncthreads();

    // S = Q K^T (19 key tiles of 16)
    f32x4 s[19];
#pragma unroll
    for (int kf = 0; kf < 19; ++kf) {
        bf16x8 kfr = *(const bf16x8*)&Ks[kf * 16 + fr][fq * 8];
        f32x4 z = {};
        s[kf] = __builtin_amdgcn_mfma_f32_16x16x32_bf16(qf, kfr, z, 0, 0, 0);
    }
    const float scale = 0.17677669529663687f;
#pragma unroll
    for (int kf = 0; kf < 19; ++kf)
#pragma unroll
        for (int j = 0; j < 4; ++j) s[kf][j] *= scale;
    if (288 + fr >= 300) {
#pragma unroll
        for (int j = 0; j < 4; ++j) s[18][j] = -1e30f;
    }
    // softmax over rows (row j spread over the 16 lanes of this fq group)
    float mx[4], sm[4], inv[4];
#pragma unroll
    for (int j = 0; j < 4; ++j) {
        mx[j] = s[0][j];
#pragma unroll
        for (int kf = 1; kf < 19; ++kf) mx[j] = fmaxf(mx[j], s[kf][j]);
    }
#pragma unroll
    for (int off = 1; off < 16; off <<= 1)
#pragma unroll
        for (int j = 0; j < 4; ++j) mx[j] = fmaxf(mx[j], __shfl_xor(mx[j], off));
#pragma unroll
    for (int j = 0; j < 4; ++j) sm[j] = 0.f;
#pragma unroll
    for (int kf = 0; kf < 19; ++kf)
#pragma unroll
        for (int j = 0; j < 4; ++j) { s[kf][j] = expf(s[kf][j] - mx[j]); sm[j] += s[kf][j]; }
#pragma unroll
    for (int off = 1; off < 16; off <<= 1)
#pragma unroll
        for (int j = 0; j < 4; ++j) sm[j] += __shfl_xor(sm[j], off);
#pragma unroll
    for (int j = 0; j < 4; ++j) inv[j] = 1.f / sm[j];

    // PV in two key-halves (Ps per-wave private; wave-synchronous LDS, DS in-order per wave)
    f32x4 o[2] = {};
#pragma unroll
    for (int half = 0; half < 2; ++half) {
        const int kfbeg = half * 10, kfend = half ? 19 : 10;
#pragma unroll
        for (int kf = kfbeg; kf < kfend; ++kf) {
            int gcol = kf * 16 + fr, lcol = gcol - half * 160;
            bool valid = gcol < 300;
#pragma unroll
            for (int j = 0; j < 4; ++j)
                Ps[w][fq * 4 + j][lcol] = valid ? f2bfbits(s[kf][j] * inv[j]) : (short)0;
        }
        if (half) {  // zero local cols 144..159 (global 304..319)
            int r = lane >> 2, c0 = 144 + (lane & 3) * 4;
#pragma unroll
            for (int i = 0; i < 4; ++i) Ps[w][r][c0 + i] = 0;
        }
#pragma unroll
        for (int ks = 0; ks < 5; ++ks) {
            bf16x8 pa = *(const bf16x8*)&Ps[w][fr][ks * 32 + fq * 8];
#pragma unroll
            for (int n = 0; n < 2; ++n) {
                bf16x8 vf = *(const bf16x8*)&Vt[n * 16 + fr][half * 160 + ks * 32 + fq * 8];
                o[n] = __builtin_amdgcn_mfma_f32_16x16x32_bf16(pa, vf, o[n], 0, 0, 0);
            }
        }
    }
    // store: row = qbase + w*16 + fq*4 + j, col d = n*16 + fr
#pragma unroll
    for (int n = 0; n < 2; ++n)
#pragma unroll
        for (int j = 0; j < 4; ++j) {
            int row = qbase + w * 16 + fq * 4 + j;
            if (row < 300)
                sa[((size_t)(b * 300 + row)) * 256 + h * 32 + n * 16 + fr] = __float2bfloat16(o[n][j]);
        }
}

// ---------------- LayerNorm(x + res); WB=1: outh=bf16(y); WB=2: outh=bf16(y+qpe) ----------------
template<int WB>
__global__ __launch_bounds__(256) void k_ln(const float* __restrict__ x,
                                            const float* __restrict__ res,
                                            const float* __restrict__ qpe,
                                            const float* __restrict__ g,
                                            const float* __restrict__ be,
                                            float* __restrict__ out,
                                            bf16* __restrict__ outh, int rows) {
    const int row = blockIdx.x;
    const int tid = threadIdx.x;
    float v = x[row * C_ + tid] + res[row * C_ + tid];
    __shared__ float red[4];
    float s = v;
#pragma unroll
    for (int off = 32; off; off >>= 1) s += __shfl_xor(s, off);
    if ((tid & 63) == 0) red[tid >> 6] = s;
    __syncthreads();
    float mean = (red[0] + red[1] + red[2] + red[3]) * (1.f / C_);
    float dv = v - mean;
    float s2 = dv * dv;
    __syncthreads();
#pragma unroll
    for (int off = 32; off; off >>= 1) s2 += __shfl_xor(s2, off);
    if ((tid & 63) == 0) red[tid >> 6] = s2;
    __syncthreads();
    float var = (red[0] + red[1] + red[2] + red[3]) * (1.f / C_);
    float rstd = 1.f / sqrtf(var + 1e-5f);
    float y = dv * rstd * g[tid] + be[tid];
    out[row * C_ + tid] = y;
    if (WB == 1) outh[row * C_ + tid] = __float2bfloat16(y);
    if (WB == 2) outh[row * C_ + tid] = __float2bfloat16(y + qpe[row * C_ + tid]);
}

// ---------------- softmax over 16 per (b,q,h) inside fused offaw buffer ----------------
__global__ __launch_bounds__(256) void k_softmax16(float* __restrict__ offaw) {
    const int t = blockIdx.x * 256 + threadIdx.x;
    if (t >= MQ_ * NH_) return;
    const int bq = t >> 3, h = t & 7;
    float* p = offaw + (size_t)bq * 384 + 256 + h * 16;
    float v[16], mx = -1e30f;
#pragma unroll
    for (int j = 0; j < 16; ++j) { v[j] = p[j]; mx = fmaxf(mx, v[j]); }
    float s = 0.f;
#pragma unroll
    for (int j = 0; j < 16; ++j) { v[j] = expf(v[j] - mx); s += v[j]; }
    float inv = 1.f / s;
#pragma unroll
    for (int j = 0; j < 16; ++j) p[j] = v[j] * inv;
}

// ---------------- deformable bilinear sampling ----------------
__global__ __launch_bounds__(256) void k_sample(const bf16* __restrict__ value,
                                                const float* __restrict__ refp,
                                                const float* __restrict__ offaw,
                                                bf16* __restrict__ out) {
    const int t = blockIdx.x * 256 + threadIdx.x;
    const int d  = t & 31;
    const int g  = t >> 5;
    const int h  = g & 7;
    const int bq = g >> 3;
    const int b  = bq / Q_;
    const int starts[4] = {0, 10000, 12500, 13125};
    const int HW[4]     = {100, 50, 25, 13};
    const float* offp = offaw + (size_t)bq * 384 + h * 32;
    const float* awp  = offaw + (size_t)bq * 384 + 256 + h * 16;
    float acc = 0.f;
#pragma unroll
    for (int l = 0; l < NL_; ++l) {
        const int Hl = HW[l], Wl = HW[l], st = starts[l];
        const float rx = refp[(bq * NL_ + l) * 2 + 0];
        const float ry = refp[(bq * NL_ + l) * 2 + 1];
        const bf16* vbase = value + ((size_t)b * LEN_ + st) * C_ + h * DH_ + d;
#pragma unroll
        for (int p = 0; p < NP_; ++p) {
            const float ox = offp[l * 8 + p * 2 + 0];
            const float oy = offp[l * 8 + p * 2 + 1];
            const float x = (rx + ox / (float)Wl) * (float)Wl - 0.5f;
            const float y = (ry + oy / (float)Hl) * (float)Hl - 0.5f;
            const float x0 = floorf(x), y0 = floorf(y);
            const float dx = x - x0, dy = y - y0;
            const int ix0 = (int)x0, iy0 = (int)y0;
            float sample = 0.f;
            { int xi = ix0,     yi = iy0;
              if (xi >= 0 && xi < Wl && yi >= 0 && yi < Hl)
                  sample += (1.f - dx) * (1.f - dy) * __bfloat162float(vbase[(yi * Wl + xi) * C_]); }
            { int xi = ix0 + 1, yi = iy0;
              if (xi >= 0 && xi < Wl && yi >= 0 && yi < Hl)
                  sample += dx * (1.f - dy) * __bfloat162float(vbase[(yi * Wl + xi) * C_]); }
            { int xi = ix0,     yi = iy0 + 1;
              if (xi >= 0 && xi < Wl && yi >= 0 && yi < Hl)
                  sample += (1.f - dx) * dy * __bfloat162float(vbase[(yi * Wl + xi) * C_]); }
            { int xi = ix0 + 1, yi = iy0 + 1;
              if (xi >= 0 && xi < Wl && yi >= 0 && yi < Hl)
                  sample += dx * dy * __bfloat162float(vbase[(yi * Wl + xi) * C_]); }
            acc += awp[l * 4 + p] * sample;
        }
    }
    out[(size_t)bq * C_ + h * DH_ + d] = __float2bfloat16(acc);
}

// ---------------- launch ----------------
extern "C" void kernel_launch(void* const* d_in, const int* in_sizes, int n_in,
                              void* d_out, int out_size, void* d_ws, size_t ws_size,
                              hipStream_t stream) {
    const float* tgt    = (const float*)d_in[0];
    const float* refp   = (const float*)d_in[1];
    const float* memory = (const float*)d_in[2];
    const float* qpe    = (const float*)d_in[3];
    const float* Wq     = (const float*)d_in[4];  const float* bq_  = (const float*)d_in[5];
    const float* Wk     = (const float*)d_in[6];  const float* bk_  = (const float*)d_in[7];
    const float* Wv     = (const float*)d_in[8];  const float* bv_  = (const float*)d_in[9];
    const float* Wo     = (const float*)d_in[10]; const float* bo_  = (const float*)d_in[11];
    const float* g1     = (const float*)d_in[12]; const float* be1  = (const float*)d_in[13];
    const float* W_off  = (const float*)d_in[14]; const float* b_off  = (const float*)d_in[15];
    const float* W_attn = (const float*)d_in[16]; const float* b_attn = (const float*)d_in[17];
    const float* W_val  = (const float*)d_in[18]; const float* b_val  = (const float*)d_in[19];
    const float* W_out  = (const float*)d_in[20]; const float* b_out  = (const float*)d_in[21];
    const float* g2     = (const float*)d_in[22]; const float* be2  = (const float*)d_in[23];
    const float* W1     = (const float*)d_in[24]; const float* b1   = (const float*)d_in[25];
    const float* W2     = (const float*)d_in[26]; const float* b2   = (const float*)d_in[27];
    const float* g3     = (const float*)d_in[28]; const float* be3  = (const float*)d_in[29];
    float* out = (float*)d_out;

    // ---- workspace layout ----
    char* base = (char*)d_ws;
    size_t off = 0;
    auto alloc = [&](size_t bytes) -> char* {
        char* p = base + off; off = (off + bytes + 255) & ~(size_t)255; return p;
    };
    float* t1       = (float*)alloc(MQ_ * C_ * 4);
    float* offaw    = (float*)alloc((size_t)MQ_ * 384 * 4);
    bf16*  query_bf = (bf16*) alloc(MQ_ * C_ * 2);
    bf16*  dsout_bf = (bf16*) alloc(MQ_ * C_ * 2);
    bf16*  Wqk_t  = (bf16*)alloc(512 * C_ * 2);     // Wq | Wk transposed
    bf16*  Wv_t   = (bf16*)alloc(C_ * C_ * 2);
    bf16*  Wo_t   = (bf16*)alloc(C_ * C_ * 2);
    bf16*  Wval_t = (bf16*)alloc(C_ * C_ * 2);
    bf16*  Woa_t  = (bf16*)alloc(384 * C_ * 2);     // W_off | W_attn transposed
    bf16*  Wout_t = (bf16*)alloc(C_ * C_ * 2);
    bf16*  W1_t   = (bf16*)alloc(C_ * DFF_ * 2);
    bf16*  W2_t   = (bf16*)alloc(DFF_ * C_ * 2);
    char*  U      = alloc((size_t)MV_ * C_ * 2);    // union region, 54.45 MB
    // phase-1 overlay
    bf16*  qk_bf  = (bf16*)(U);                     // tgt + qpe
    bf16*  tgt_bf = (bf16*)(U + 1228800);
    bf16*  qkbuf  = (bf16*)(U + 2457600);           // [2400][512] q|k
    bf16*  vb     = (bf16*)(U + 4915200);           // [2400][256]
    bf16*  sa_bf  = (bf16*)(U + 6144000);
    float* saO    = (float*)(U + 7372800);
    // phase-2 overlay
    bf16*  value_bf = (bf16*)(U);
    // phase-3 overlay
    float* ca     = (float*)(U);
    float* t2     = (float*)(U + 2457600);
    bf16*  t2_bf  = (bf16*) (U + 4915200);
    bf16*  ff1_bf = (bf16*) (U + 6144000);
    float* ff2    = (float*)(U + 11059200);

    // ---- prep (2 launches) ----
    k_wtall<<<992, 256, 0, stream>>>(Wq, Wk, Wv, Wo, W_val, W_off, W_attn, W_out, W1, W2,
                                     Wqk_t, Wv_t, Wo_t, Wval_t, Woa_t, Wout_t, W1_t, W2_t);
    k_dualcvt<<<300, 256, 0, stream>>>(tgt, qpe, qk_bf, tgt_bf, MQ_ * C_ / 8);

    // ---- self-attention ----
    k_gmm64<0,1><<<dim3(8, 38), 256, 0, stream>>>(qk_bf,  Wqk_t, bq_, bk_, 256, nullptr, qkbuf, MQ_, 512, C_);
    k_gmm64<0,1><<<dim3(4, 38), 256, 0, stream>>>(tgt_bf, Wv_t,  bv_, bv_, 256, nullptr, vb,    MQ_, 256, C_);
    k_attn<<<dim3(5, 64), 256, 0, stream>>>(qkbuf, vb, sa_bf);
    k_gmm64<0,0><<<dim3(4, 38), 256, 0, stream>>>(sa_bf, Wo_t, bo_, bo_, 256, saO, nullptr, MQ_, 256, C_);
    k_ln<2><<<2400, 256, 0, stream>>>(tgt, saO, qpe, g1, be1, t1, query_bf, MQ_);

    // ---- deformable cross-attention ----
    k_gmm64<0,0><<<dim3(6, 38), 256, 0, stream>>>(query_bf, Woa_t, b_off, b_attn, 256, offaw, nullptr, MQ_, 384, C_);
    k_softmax16<<<75, 256, 0, stream>>>(offaw);
    k_gmmV<<<dim3(2, 831), 256, 0, stream>>>(memory, Wval_t, b_val, value_bf, MV_, C_, C_);
    k_sample<<<2400, 256, 0, stream>>>(value_bf, refp, offaw, dsout_bf);
    k_gmm64<0,0><<<dim3(4, 38), 256, 0, stream>>>(dsout_bf, Wout_t, b_out, b_out, 256, ca, nullptr, MQ_, 256, C_);
    k_ln<1><<<2400, 256, 0, stream>>>(t1, ca, nullptr, g2, be2, t2, t2_bf, MQ_);

    // ---- FFN ----
    k_gmm64<1,1><<<dim3(16, 38), 256, 0, stream>>>(t2_bf, W1_t, b1, b1, DFF_, nullptr, ff1_bf, MQ_, DFF_, C_);
    k_gmm64<0,0><<<dim3(4, 38), 256, 0, stream>>>(ff1_bf, W2_t, b2, b2, 256, ff2, nullptr, MQ_, C_, DFF_);
    k_ln<0><<<2400, 256, 0, stream>>>(t2, ff2, nullptr, g3, be3, out, nullptr, MQ_);
}